// Round 1
// baseline (1012.827 us; speedup 1.0000x reference)
//
#include <hip/hip_runtime.h>
#include <math.h>

#define NB 128
#define CC 64
#define TT 128
#define VV 25
#define SS 3
#define REL 8
#define INNER 24   // REL*SS
#define QKD 48     // 2*INNER

__global__ __launch_bounds__(256, 2)
void agcn_fused_kernel(const float* __restrict__ x,
                       const float* __restrict__ PA,
                       const float* __restrict__ ln_g, const float* __restrict__ ln_b,
                       const float* __restrict__ Wqk, const float* __restrict__ bqk,
                       const float* __restrict__ conv_w, const float* __restrict__ conv_b,
                       const float* __restrict__ bn_g, const float* __restrict__ bn_b,
                       const float* __restrict__ bn_m, const float* __restrict__ bn_v,
                       float* __restrict__ out)
{
    const int bid = blockIdx.x;
    const int n = bid / TT, t = bid % TT;
    const int tid = threadIdx.x;

    // LDS: xv (padded 65) + z + union region
    __shared__ float xv[VV * 65];          // 6500 B   [v][c]
    __shared__ float zbuf[SS * VV * 64];   // 19200 B  [h][i][c]
    __shared__ float uni[12480];           // 49920 B  phase1: Wt|yn|qk|A ; phase2: convW ; phase3: res

    float* Wt   = uni;                 // [c][49]  3136 floats
    float* yn   = uni + 3136;          // [v][64]  1600
    float* qkb  = uni + 3136 + 1600;   // [v][48]  1200
    float* Abuf = uni + 3136 + 1600 + 1200; // [h][i][j] 1875

    // ---- load x tile -> xv[v][c] ----
    const float* xbase = x + ((size_t)n * CC * TT + t) * VV; // elem (c,v): + c*TT*VV + v
    for (int idx = tid; idx < CC * VV; idx += 256) {
        int c = idx / VV, v = idx % VV;
        xv[v * 65 + c] = xbase[(size_t)c * TT * VV + v];
    }
    // ---- load Wqk transposed -> Wt[c][49] ----
    for (int idx = tid; idx < QKD * CC; idx += 256) {
        int j = idx / CC, c = idx % CC;
        Wt[c * 49 + j] = Wqk[idx];
    }
    __syncthreads();

    // ---- LayerNorm over C per (v); wave w handles v = w, w+4, ... ----
    {
        int wave = tid >> 6, lane = tid & 63;
        for (int v = wave; v < VV; v += 4) {
            float val = xv[v * 65 + lane];
            float s = val;
            for (int off = 32; off; off >>= 1) s += __shfl_xor(s, off);
            float mu = s * (1.0f / 64.0f);
            float d = val - mu;
            float s2 = d * d;
            for (int off = 32; off; off >>= 1) s2 += __shfl_xor(s2, off);
            float rstd = rsqrtf(s2 * (1.0f / 64.0f) + 1e-5f);
            yn[v * 64 + lane] = d * rstd * ln_g[lane] + ln_b[lane];
        }
    }
    __syncthreads();

    // ---- qk = yn @ Wqk^T + bqk -> qkb[v][j] ----
    for (int idx = tid; idx < VV * QKD; idx += 256) {
        int v = idx / QKD, j = idx % QKD;
        float acc = bqk[j];
        const float* yr = &yn[v * 64];
        #pragma unroll
        for (int c = 0; c < CC; ++c) acc += yr[c] * Wt[c * 49 + j];
        qkb[v * 48 + j] = acc;
    }
    __syncthreads();

    // ---- dots (pre-softmax) -> Abuf ----
    const float scale = 0.35355339059327373f; // 8^-0.5
    for (int idx = tid; idx < SS * VV * VV; idx += 256) {
        int h = idx / (VV * VV), r = idx % (VV * VV);
        int i = r / VV, j = r % VV;
        const float* q = &qkb[i * 48 + h * REL];
        const float* k = &qkb[j * 48 + INNER + h * REL];
        float d = 0.f;
        #pragma unroll
        for (int dd = 0; dd < REL; ++dd) d += q[dd] * k[dd];
        Abuf[idx] = d * scale;
    }
    __syncthreads();

    // ---- softmax per (h,i) row, then * PA ----
    if (tid < SS * VV) {
        int h = tid / VV, i = tid % VV;
        float* row = &Abuf[h * 625 + i * 25];
        const float* pa = &PA[h * 625 + i * 25];
        float m = row[0];
        #pragma unroll
        for (int j = 1; j < VV; ++j) m = fmaxf(m, row[j]);
        float e[VV];
        float s = 0.f;
        #pragma unroll
        for (int j = 0; j < VV; ++j) { e[j] = __expf(row[j] - m); s += e[j]; }
        float inv = 1.0f / s;
        #pragma unroll
        for (int j = 0; j < VV; ++j) row[j] = e[j] * inv * pa[j];
    }
    __syncthreads();

    // ---- z[h][i][c] = sum_j A[h][i][j] * xv[j][c] ----
    for (int idx = tid; idx < SS * VV * 64; idx += 256) {
        int h = idx / (VV * 64), r = idx % (VV * 64);
        int i = r / 64, c = r % 64;
        const float* arow = &Abuf[(h * VV + i) * VV];
        float acc = 0.f;
        #pragma unroll
        for (int j = 0; j < VV; ++j) acc += arow[j] * xv[j * 65 + c];
        zbuf[idx] = acc;
    }
    __syncthreads();

    // ---- stage conv_w transposed -> uni as cw[h][ci][o] with o-dim padded 65 ----
    for (int idx = tid; idx < SS * CC * CC; idx += 256) {
        int h = idx / (CC * CC), r = idx % (CC * CC);
        int o = r / CC, ci = r % CC;
        uni[(h * CC + ci) * 65 + o] = conv_w[idx];
    }
    __syncthreads();

    // ---- out[o][v] = sum_{h,c} z[h][v][c] * cw[h][c][o]; then BN+res+ReLU ----
    {
        int o = tid & 63, vg = tid >> 6;
        float acc[7];
        #pragma unroll
        for (int k = 0; k < 7; ++k) acc[k] = 0.f;

        for (int h = 0; h < SS; ++h) {
            const float* zh = &zbuf[h * VV * 64];
            const float* wh = &uni[h * CC * 65];
            #pragma unroll 4
            for (int c4 = 0; c4 < 16; ++c4) {
                float w0 = wh[(c4 * 4 + 0) * 65 + o];
                float w1 = wh[(c4 * 4 + 1) * 65 + o];
                float w2 = wh[(c4 * 4 + 2) * 65 + o];
                float w3 = wh[(c4 * 4 + 3) * 65 + o];
                #pragma unroll
                for (int k = 0; k < 7; ++k) {
                    int v = vg + 4 * k;
                    int vc = (v < VV) ? v : 0;
                    const float4 zv = *(const float4*)&zh[vc * 64 + c4 * 4];
                    acc[k] += w0 * zv.x + w1 * zv.y + w2 * zv.z + w3 * zv.w;
                }
            }
        }

        __syncthreads();   // all conv_w reads done; safe to overwrite uni with res

        float bscale = bn_g[o] * rsqrtf(bn_v[o] + 1e-5f);
        float bbias  = bn_b[o] - bn_m[o] * bscale;
        float cb = conv_b[o] + conv_b[64 + o] + conv_b[128 + o];
        float* res = uni; // [c][25]
        #pragma unroll
        for (int k = 0; k < 7; ++k) {
            int v = vg + 4 * k;
            if (v < VV) {
                float val = (acc[k] + cb) * bscale + bbias + xv[v * 65 + o];
                res[o * 25 + v] = fmaxf(val, 0.f);
            }
        }
    }
    __syncthreads();

    // ---- coalesced store ----
    {
        const float* res = uni;
        float* ob = out + ((size_t)n * CC * TT + t) * VV;
        for (int idx = tid; idx < CC * VV; idx += 256) {
            int c = idx / VV, v = idx % VV;
            ob[(size_t)c * TT * VV + v] = res[idx];
        }
    }
}

extern "C" void kernel_launch(void* const* d_in, const int* in_sizes, int n_in,
                              void* d_out, int out_size, void* d_ws, size_t ws_size,
                              hipStream_t stream) {
    const float* x      = (const float*)d_in[0];
    const float* PA     = (const float*)d_in[1];
    const float* ln_g   = (const float*)d_in[2];
    const float* ln_b   = (const float*)d_in[3];
    const float* Wqk    = (const float*)d_in[4];
    const float* bqk    = (const float*)d_in[5];
    const float* conv_w = (const float*)d_in[6];
    const float* conv_b = (const float*)d_in[7];
    const float* bn_g   = (const float*)d_in[8];
    const float* bn_b   = (const float*)d_in[9];
    const float* bn_m   = (const float*)d_in[10];
    const float* bn_v   = (const float*)d_in[11];
    float* outp = (float*)d_out;

    dim3 grid(NB * TT);
    dim3 block(256);
    agcn_fused_kernel<<<grid, block, 0, stream>>>(x, PA, ln_g, ln_b, Wqk, bqk,
                                                  conv_w, conv_b, bn_g, bn_b,
                                                  bn_m, bn_v, outp);
}

// Round 2
// 640.550 us; speedup vs baseline: 1.5812x; 1.5812x over previous
//
#include <hip/hip_runtime.h>
#include <math.h>

#define NB 128
#define CC 64
#define TT 128
#define VV 25
#define SS 3
#define REL 8
#define INNER 24   // REL*SS
#define QKD 48     // 2*INNER
#define XVP 68     // xv row stride: 16B-aligned for b128, spreads banks

// uni layout (floats), phases overlay dead buffers:
//   phase A (LN/qk):  Wt[0..3136) [c][49] | yn[3136..4736) [v][64] | qkb[4736..5986) [v][50]
//   phase B (dots):   qkb | Abuf[5986..7861) [h][i][j]
//   phase C (z):      Abuf read | zbuf[0..4800) [h][i][c]  (Wt/yn/qkb dead)
//   phase D (conv):   zbuf | cwt[5986..8066) [32][65]      (Abuf dead)
//   phase E (store):  res[0..1600) [o][v]                  (zbuf dead)
#define UNI_FLOATS 8066

__global__ __launch_bounds__(256, 4)
void agcn_fused_kernel(const float* __restrict__ x,
                       const float* __restrict__ PA,
                       const float* __restrict__ ln_g, const float* __restrict__ ln_b,
                       const float* __restrict__ Wqk, const float* __restrict__ bqk,
                       const float* __restrict__ conv_w, const float* __restrict__ conv_b,
                       const float* __restrict__ bn_g, const float* __restrict__ bn_b,
                       const float* __restrict__ bn_m, const float* __restrict__ bn_v,
                       float* __restrict__ out)
{
    const int bid = blockIdx.x;
    const int n = bid / TT, t = bid % TT;
    const int tid = threadIdx.x;

    __shared__ float xv[VV * XVP];     // 1700 floats, [v][c] rows stride 68
    __shared__ float uni[UNI_FLOATS];  // 8066 floats

    float* Wt   = uni;            // [64][49]
    float* yn   = uni + 3136;     // [25][64]
    float* qkb  = uni + 4736;     // [25][50]
    float* Abuf = uni + 5986;     // [3][25][25]
    float* zbuf = uni;            // [3][25][64] (phase C+)
    float* cwt  = uni + 5986;     // [32][65]   (phase D)
    float* res  = uni;            // [64][25]   (phase E)

    // ---- load x tile -> xv[v][c] ----
    const float* xbase = x + ((size_t)n * CC * TT + t) * VV;
    for (int idx = tid; idx < CC * VV; idx += 256) {
        int c = idx / VV, v = idx % VV;
        xv[v * XVP + c] = xbase[(size_t)c * TT * VV + v];
    }
    // ---- load Wqk transposed -> Wt[c][49] ----
    for (int idx = tid; idx < QKD * CC; idx += 256) {
        int j = idx / CC, c = idx % CC;
        Wt[c * 49 + j] = Wqk[idx];
    }
    __syncthreads();

    // ---- LayerNorm over C per joint v ----
    {
        int wave = tid >> 6, lane = tid & 63;
        for (int v = wave; v < VV; v += 4) {
            float val = xv[v * XVP + lane];
            float s = val;
            for (int off = 32; off; off >>= 1) s += __shfl_xor(s, off);
            float mu = s * (1.0f / 64.0f);
            float d = val - mu;
            float s2 = d * d;
            for (int off = 32; off; off >>= 1) s2 += __shfl_xor(s2, off);
            float rstd = rsqrtf(s2 * (1.0f / 64.0f) + 1e-5f);
            yn[v * 64 + lane] = d * rstd * ln_g[lane] + ln_b[lane];
        }
    }
    __syncthreads();

    // ---- qk = yn @ Wqk^T + bqk -> qkb[v][j] (stride 50) ----
    for (int idx = tid; idx < VV * QKD; idx += 256) {
        int v = idx / QKD, j = idx % QKD;
        float acc = bqk[j];
        const float* yr = &yn[v * 64];
        #pragma unroll
        for (int c = 0; c < CC; ++c) acc += yr[c] * Wt[c * 49 + j];
        qkb[v * 50 + j] = acc;
    }
    __syncthreads();

    // ---- dots -> Abuf ----
    const float scale = 0.35355339059327373f; // 8^-0.5
    for (int idx = tid; idx < SS * VV * VV; idx += 256) {
        int h = idx / (VV * VV), r = idx % (VV * VV);
        int i = r / VV, j = r % VV;
        const float* q = &qkb[i * 50 + h * REL];
        const float* k = &qkb[j * 50 + INNER + h * REL];
        float d = 0.f;
        #pragma unroll
        for (int dd = 0; dd < REL; ++dd) d += q[dd] * k[dd];
        Abuf[idx] = d * scale;
    }
    __syncthreads();

    // ---- softmax per (h,i) row, then * PA ----
    if (tid < SS * VV) {
        int h = tid / VV, i = tid % VV;
        float* row = &Abuf[h * 625 + i * 25];
        const float* pa = &PA[h * 625 + i * 25];
        float m = row[0];
        #pragma unroll
        for (int j = 1; j < VV; ++j) m = fmaxf(m, row[j]);
        float e[VV];
        float s = 0.f;
        #pragma unroll
        for (int j = 0; j < VV; ++j) { e[j] = __expf(row[j] - m); s += e[j]; }
        float inv = 1.0f / s;
        #pragma unroll
        for (int j = 0; j < VV; ++j) row[j] = e[j] * inv * pa[j];
    }
    __syncthreads();

    // ---- z[h][i][c4] = sum_j A[h][i][j] * xv[j][c4] (float4) ----
    // overlays Wt/yn/qkb (dead); reads Abuf (disjoint region)
    for (int idx = tid; idx < SS * VV * 16; idx += 256) {
        int c4 = idx & 15;
        int r  = idx >> 4;            // h*25 + i
        const float* arow = &Abuf[r * VV];
        float4 acc = make_float4(0.f, 0.f, 0.f, 0.f);
        #pragma unroll
        for (int j = 0; j < VV; ++j) {
            float a = arow[j];
            const float4 xj = *(const float4*)&xv[j * XVP + c4 * 4];
            acc.x += a * xj.x; acc.y += a * xj.y;
            acc.z += a * xj.z; acc.w += a * xj.w;
        }
        *(float4*)&zbuf[r * 64 + c4 * 4] = acc;
    }
    __syncthreads();

    // ---- conv: out[o][v] = sum_{h,c} z[h][v][c] * w[h][o][c], chunked staging ----
    {
        const int o = tid & 63, vg = tid >> 6;
        float acc[7];
        #pragma unroll
        for (int k = 0; k < 7; ++k) acc[k] = 0.f;

        for (int hh = 0; hh < 6; ++hh) {
            const int h = hh >> 1, half = hh & 1;
            // stage 32 c-rows transposed: cwt[c][o], coalesced read, stride-65 write
            #pragma unroll
            for (int it = 0; it < 8; ++it) {
                int idx = it * 256 + tid;
                int o2 = idx >> 5, c = idx & 31;
                cwt[c * 65 + o2] = conv_w[h * 4096 + o2 * 64 + half * 32 + c];
            }
            __syncthreads();

            const float* zh = &zbuf[h * 1600 + half * 32];
            #pragma unroll
            for (int c4 = 0; c4 < 8; ++c4) {
                float w0 = cwt[(c4 * 4 + 0) * 65 + o];
                float w1 = cwt[(c4 * 4 + 1) * 65 + o];
                float w2 = cwt[(c4 * 4 + 2) * 65 + o];
                float w3 = cwt[(c4 * 4 + 3) * 65 + o];
                #pragma unroll
                for (int k = 0; k < 7; ++k) {
                    int v = vg + 4 * k;
                    int vc = (v < VV) ? v : 0;
                    const float4 zv = *(const float4*)&zh[vc * 64 + c4 * 4];
                    acc[k] += w0 * zv.x + w1 * zv.y + w2 * zv.z + w3 * zv.w;
                }
            }
            __syncthreads();  // chunk reads done before restage / res overlay
        }

        // ---- BN + residual + ReLU -> res[o][v] (overlays zbuf, synced) ----
        float bscale = bn_g[o] * rsqrtf(bn_v[o] + 1e-5f);
        float bbias  = bn_b[o] - bn_m[o] * bscale;
        float cb = conv_b[o] + conv_b[64 + o] + conv_b[128 + o];
        #pragma unroll
        for (int k = 0; k < 7; ++k) {
            int v = vg + 4 * k;
            if (v < VV) {
                float val = (acc[k] + cb) * bscale + bbias + xv[v * XVP + o];
                res[o * 25 + v] = fmaxf(val, 0.f);
            }
        }
    }
    __syncthreads();

    // ---- coalesced store ----
    {
        float* ob = out + ((size_t)n * CC * TT + t) * VV;
        for (int idx = tid; idx < CC * VV; idx += 256) {
            int c = idx / VV, v = idx % VV;
            ob[(size_t)c * TT * VV + v] = res[idx];
        }
    }
}

extern "C" void kernel_launch(void* const* d_in, const int* in_sizes, int n_in,
                              void* d_out, int out_size, void* d_ws, size_t ws_size,
                              hipStream_t stream) {
    const float* x      = (const float*)d_in[0];
    const float* PA     = (const float*)d_in[1];
    const float* ln_g   = (const float*)d_in[2];
    const float* ln_b   = (const float*)d_in[3];
    const float* Wqk    = (const float*)d_in[4];
    const float* bqk    = (const float*)d_in[5];
    const float* conv_w = (const float*)d_in[6];
    const float* conv_b = (const float*)d_in[7];
    const float* bn_g   = (const float*)d_in[8];
    const float* bn_b   = (const float*)d_in[9];
    const float* bn_m   = (const float*)d_in[10];
    const float* bn_v   = (const float*)d_in[11];
    float* outp = (float*)d_out;

    dim3 grid(NB * TT);
    dim3 block(256);
    agcn_fused_kernel<<<grid, block, 0, stream>>>(x, PA, ln_g, ln_b, Wqk, bqk,
                                                  conv_w, conv_b, bn_g, bn_b,
                                                  bn_m, bn_v, outp);
}